// Round 4
// baseline (629.235 us; speedup 1.0000x reference)
//
#include <hip/hip_runtime.h>
#include <hip/hip_bf16.h>
#include <stdint.h>
#include <math.h>

#define NTOK   2048
#define DDIM   1024
#define ENUM   8
#define IDIM   2048
#define TWOI   4096
#define TOPKN  4
#define CAPROWS 9216   // max padded routed rows: 8192 + 8*127 = 9208 -> 9216

typedef unsigned short ushort_t;
typedef __attribute__((ext_vector_type(8))) short short8;
typedef __attribute__((ext_vector_type(4))) float f4;

__device__ inline ushort_t f2bf(float f) {
    union { float f; uint32_t u; } v; v.f = f;
    uint32_t u = v.u;
    u += 0x7FFFu + ((u >> 16) & 1u);   // RNE
    return (ushort_t)(u >> 16);
}

// packed fp32x2 -> bf16x2 (v_cvt_pk_bf16_f32 on gfx950), lo in low 16 bits
__device__ inline uint32_t pk2(float lo, float hi) {
    __hip_bfloat162 h = __float22bfloat162_rn(make_float2(lo, hi));
    union { __hip_bfloat162 h; uint32_t u; } c; c.h = h;
    return c.u;
}

// stage 8 consecutive fp32 from global -> 8 bf16 (16 B) into LDS
__device__ inline void stage_f32row(const float* __restrict__ gsrc, ushort_t* ldst) {
    float4 v0 = ((const float4*)gsrc)[0];
    float4 v1 = ((const float4*)gsrc)[1];
    uint4 o;
    o.x = pk2(v0.x, v0.y); o.y = pk2(v0.z, v0.w);
    o.z = pk2(v1.x, v1.y); o.w = pk2(v1.z, v1.w);
    *((uint4*)ldst) = o;
}

// async global->LDS 16B/lane (gfx950). LDS dest = wave-uniform base + lane*16.
__device__ inline void gload16(const ushort_t* g, ushort_t* l) {
    __builtin_amdgcn_global_load_lds(
        (const __attribute__((address_space(1))) uint32_t*)(uintptr_t)g,
        (__attribute__((address_space(3))) uint32_t*)(uint32_t)(uintptr_t)l,
        16, 0, 0);
}

__global__ void zero_meta_kernel(int* meta) {
    if (blockIdx.x == 0 && threadIdx.x < 64) meta[threadIdx.x] = 0;
}

// ---------------- router: fp64 logits (top-4 robust vs fp32 ref noise), fp32 softmax ----
__global__ void router_kernel(const float* __restrict__ x, const float* __restrict__ rw,
                              const float* __restrict__ rb, int* __restrict__ topk_idx,
                              float* __restrict__ topk_w, int* __restrict__ counts) {
    int n = (blockIdx.x * 256 + threadIdx.x) >> 6;   // one wave per token
    int lane = threadIdx.x & 63;
    const float* xr = x + (size_t)n * DDIM;
    double p[ENUM];
#pragma unroll
    for (int e = 0; e < ENUM; ++e) p[e] = 0.0;
    for (int d0 = 0; d0 < DDIM; d0 += 64) {
        double xv = (double)xr[d0 + lane];
#pragma unroll
        for (int e = 0; e < ENUM; ++e) p[e] += xv * (double)rw[e * DDIM + d0 + lane];
    }
#pragma unroll
    for (int e = 0; e < ENUM; ++e) {
        double v = p[e];
#pragma unroll
        for (int off = 32; off > 0; off >>= 1) v += __shfl_xor(v, off, 64);
        p[e] = v + (double)rb[e];
    }
    if (lane == 0) {
        int id[TOPKN]; double lv[TOPKN]; unsigned used = 0;
#pragma unroll
        for (int k = 0; k < TOPKN; ++k) {
            double best = -INFINITY; int bi = 0;
            for (int e = 0; e < ENUM; ++e)
                if (!((used >> e) & 1u) && p[e] > best) { best = p[e]; bi = e; }
            used |= 1u << bi; id[k] = bi; lv[k] = best;
        }
        float lf[TOPKN]; float s = 0.f; float w[TOPKN];
#pragma unroll
        for (int k = 0; k < TOPKN; ++k) lf[k] = (float)lv[k];
#pragma unroll
        for (int k = 0; k < TOPKN; ++k) { w[k] = expf(lf[k] - lf[0]); s += w[k]; }
        float inv = 1.f / s;
#pragma unroll
        for (int k = 0; k < TOPKN; ++k) {
            topk_idx[n * TOPKN + k] = id[k];
            topk_w[n * TOPKN + k] = w[k] * inv;
            atomicAdd(&counts[id[k]], 1);
        }
    }
}

// ---------------- assign routed rows (scan inlined: every thread computes prefix) ----
__global__ void assign_kernel(const int* __restrict__ topk_idx, const float* __restrict__ topk_w,
                              const int* __restrict__ counts, int* __restrict__ fill,
                              int* __restrict__ row_token, float* __restrict__ row_weight,
                              int* __restrict__ row_of_pair,
                              int* __restrict__ base, int* __restrict__ padcnt,
                              int* __restrict__ totalp) {
    int baseL[ENUM]; int run = 0;
#pragma unroll
    for (int e = 0; e < ENUM; ++e) {
        baseL[e] = run;
        run += (counts[e] + 127) & ~127;
    }
    int n = blockIdx.x * 256 + threadIdx.x;
    if (n == 0) {
#pragma unroll
        for (int e = 0; e < ENUM; ++e) {
            base[e] = baseL[e];
            padcnt[e] = (counts[e] + 127) & ~127;
        }
        *totalp = run;
    }
    if (n >= NTOK) return;
    for (int k = 0; k < TOPKN; ++k) {
        int e = topk_idx[n * TOPKN + k];
        int pos = atomicAdd(&fill[e], 1);
        int row = baseL[e] + pos;
        row_token[row] = n;
        row_weight[row] = topk_w[n * TOPKN + k];
        row_of_pair[n * TOPKN + k] = row;
    }
}

// ---------------- gather tokens -> bf16 A matrix (zero pad rows) ----------------
__global__ void gather_kernel(const float* __restrict__ x, const int* __restrict__ row_token,
                              const int* __restrict__ base, const int* __restrict__ counts,
                              const int* __restrict__ padcnt, const int* __restrict__ totalp,
                              ushort_t* __restrict__ A) {
    int r = blockIdx.x;
    if (r >= *totalp) return;
    int e = 0;
#pragma unroll
    for (int i = 0; i < ENUM; ++i) if (r >= base[i] + padcnt[i]) e = i + 1;
    bool valid = (r - base[e]) < counts[e];
    int t = threadIdx.x;
    float4 v = make_float4(0.f, 0.f, 0.f, 0.f);
    if (valid) {
        int n = row_token[r];
        v = ((const float4*)(x + (size_t)n * DDIM))[t];
    }
    ushort4 o; o.x = f2bf(v.x); o.y = f2bf(v.y); o.z = f2bf(v.z); o.w = f2bf(v.w);
    ((ushort4*)(A + (size_t)r * DDIM))[t] = o;
}

// ---------------- GEMM1 fused: act = swiglu(A@Wgate^T+bg, A@Wup^T+bu), cvt fused -------
// A (bf16) staged via async DMA; Wgate/Wup staged fp32->bf16 inline (v_cvt_pk_bf16_f32).
__global__ __launch_bounds__(256, 2)
void gemm1_kernel(const ushort_t* __restrict__ A, const float* __restrict__ gup,
                  const float* __restrict__ gub, ushort_t* __restrict__ act,
                  const int* __restrict__ base, const int* __restrict__ padcnt) {
    const int e = blockIdx.z;
    const int mt = blockIdx.y;
    if (mt * 128 >= padcnt[e]) return;
    const int nt = blockIdx.x;               // 0..15 -> cols of I dim
    const int row0 = base[e] + mt * 128;
    __shared__ ushort_t ldsA[128 * 32];
    __shared__ ushort_t ldsG[128 * 32];
    __shared__ ushort_t ldsU[128 * 32];
    f4 accg[4][4], accu[4][4];
    const f4 zero = {0.f, 0.f, 0.f, 0.f};
#pragma unroll
    for (int i = 0; i < 4; ++i)
#pragma unroll
        for (int j = 0; j < 4; ++j) { accg[i][j] = zero; accu[i][j] = zero; }

    const int t = threadIdx.x;
    const int lane = t & 63;
    const int wid = t >> 6;
    const int wm = wid >> 1, wn = wid & 1;
    const int r15 = lane & 15, quad = lane >> 4;
    const int sr = t >> 2;
    const int sc = (t & 3) << 3;

    const ushort_t* Ag = A + (size_t)row0 * DDIM;
    const ushort_t* aA  = Ag + (size_t)sr * DDIM + sc;
    const ushort_t* aA2 = Ag + (size_t)(sr + 64) * DDIM + sc;
    // fp32 weight row pointers (gate rows 0..2047, up rows 2048..4095 within expert)
    const float* gG  = gup + ((size_t)e * TWOI + nt * 128 + sr) * DDIM + sc;
    const float* gG2 = gG + (size_t)64 * DDIM;
    const float* gU  = gup + ((size_t)e * TWOI + IDIM + nt * 128 + sr) * DDIM + sc;
    const float* gU2 = gU + (size_t)64 * DDIM;

    ushort_t* lA  = ldsA + sr * 32 + sc;  ushort_t* lA2 = ldsA + (sr + 64) * 32 + sc;
    ushort_t* lG  = ldsG + sr * 32 + sc;  ushort_t* lG2 = ldsG + (sr + 64) * 32 + sc;
    ushort_t* lU  = ldsU + sr * 32 + sc;  ushort_t* lU2 = ldsU + (sr + 64) * 32 + sc;

    for (int k0 = 0; k0 < DDIM; k0 += 32) {
        __syncthreads();
        gload16(aA + k0, lA);   gload16(aA2 + k0, lA2);
        stage_f32row(gG + k0, lG);   stage_f32row(gG2 + k0, lG2);
        stage_f32row(gU + k0, lU);   stage_f32row(gU2 + k0, lU2);
        __syncthreads();
        short8 af[4], gf[4], uf[4];
#pragma unroll
        for (int i = 0; i < 4; ++i) {
            af[i] = *(const short8*)(ldsA + (wm * 64 + i * 16 + r15) * 32 + quad * 8);
            gf[i] = *(const short8*)(ldsG + (wn * 64 + i * 16 + r15) * 32 + quad * 8);
            uf[i] = *(const short8*)(ldsU + (wn * 64 + i * 16 + r15) * 32 + quad * 8);
        }
#pragma unroll
        for (int mi = 0; mi < 4; ++mi)
#pragma unroll
            for (int ni = 0; ni < 4; ++ni) {
                accg[mi][ni] = __builtin_amdgcn_mfma_f32_16x16x32_bf16(af[mi], gf[ni], accg[mi][ni], 0, 0, 0);
                accu[mi][ni] = __builtin_amdgcn_mfma_f32_16x16x32_bf16(af[mi], uf[ni], accu[mi][ni], 0, 0, 0);
            }
    }

    const int colbase = nt * 128 + wn * 64;
    const int rowbase = row0 + wm * 64;
#pragma unroll
    for (int ni = 0; ni < 4; ++ni) {
        const int col = colbase + ni * 16 + r15;            // 0..2047 (I dim)
        const float bg = gub[e * TWOI + col];
        const float bu = gub[e * TWOI + IDIM + col];
#pragma unroll
        for (int mi = 0; mi < 4; ++mi) {
#pragma unroll
            for (int r = 0; r < 4; ++r) {
                const int row = rowbase + mi * 16 + quad * 4 + r;
                float g = fminf(accg[mi][ni][r] + bg, 7.0f);
                float u = fminf(fmaxf(accu[mi][ni][r] + bu, -7.0f), 7.0f);
                float a = (u + 1.0f) * g / (1.0f + __expf(-1.702f * g));
                act[(size_t)row * IDIM + col] = f2bf(a);
            }
        }
    }
}

// ---------------- GEMM2: contrib = (act @ Wd^T + bias) * route_weight, cvt fused -------
__global__ __launch_bounds__(256, 2)
void gemm2_kernel(const ushort_t* __restrict__ A, const float* __restrict__ dwn,
                  const float* __restrict__ dwb, const float* __restrict__ row_weight,
                  float* __restrict__ contrib,
                  const int* __restrict__ base, const int* __restrict__ padcnt) {
    const int e = blockIdx.z;
    const int mt = blockIdx.y;
    if (mt * 128 >= padcnt[e]) return;
    const int nt = blockIdx.x;
    const int row0 = base[e] + mt * 128;
    __shared__ ushort_t ldsA[128 * 32];
    __shared__ ushort_t ldsB[128 * 32];
    f4 acc[4][4];
    const f4 zero = {0.f, 0.f, 0.f, 0.f};
#pragma unroll
    for (int i = 0; i < 4; ++i)
#pragma unroll
        for (int j = 0; j < 4; ++j) acc[i][j] = zero;

    const int t = threadIdx.x;
    const int lane = t & 63;
    const int wid = t >> 6;
    const int wm = wid >> 1, wn = wid & 1;
    const int r15 = lane & 15, quad = lane >> 4;
    const int sr = t >> 2;
    const int sc = (t & 3) << 3;

    const ushort_t* Ag = A + (size_t)row0 * IDIM;
    const ushort_t* aA  = Ag + (size_t)sr * IDIM + sc;
    const ushort_t* aA2 = Ag + (size_t)(sr + 64) * IDIM + sc;
    const float* gB  = dwn + ((size_t)e * DDIM + nt * 128 + sr) * IDIM + sc;
    const float* gB2 = gB + (size_t)64 * IDIM;
    ushort_t* lA  = ldsA + sr * 32 + sc;  ushort_t* lA2 = ldsA + (sr + 64) * 32 + sc;
    ushort_t* lB  = ldsB + sr * 32 + sc;  ushort_t* lB2 = ldsB + (sr + 64) * 32 + sc;

    for (int k0 = 0; k0 < IDIM; k0 += 32) {
        __syncthreads();
        gload16(aA + k0, lA);   gload16(aA2 + k0, lA2);
        stage_f32row(gB + k0, lB);   stage_f32row(gB2 + k0, lB2);
        __syncthreads();
        short8 af[4], bfv[4];
#pragma unroll
        for (int i = 0; i < 4; ++i) {
            af[i]  = *(const short8*)(ldsA + (wm * 64 + i * 16 + r15) * 32 + quad * 8);
            bfv[i] = *(const short8*)(ldsB + (wn * 64 + i * 16 + r15) * 32 + quad * 8);
        }
#pragma unroll
        for (int mi = 0; mi < 4; ++mi)
#pragma unroll
            for (int ni = 0; ni < 4; ++ni)
                acc[mi][ni] = __builtin_amdgcn_mfma_f32_16x16x32_bf16(af[mi], bfv[ni], acc[mi][ni], 0, 0, 0);
    }

    const int colbase = nt * 128 + wn * 64;
    const int rowbase = row0 + wm * 64;
#pragma unroll
    for (int mi = 0; mi < 4; ++mi) {
#pragma unroll
        for (int r = 0; r < 4; ++r) {
            const int row = rowbase + mi * 16 + quad * 4 + r;
            const float w = row_weight[row];
#pragma unroll
            for (int ni = 0; ni < 4; ++ni) {
                const int col = colbase + ni * 16 + r15;
                contrib[(size_t)row * DDIM + col] = (acc[mi][ni][r] + dwb[e * DDIM + col]) * w;
            }
        }
    }
}

// ---------------- combine 4 contributions per token ----------------
__global__ void combine_kernel(const float* __restrict__ contrib, const int* __restrict__ row_of_pair,
                               float* __restrict__ out) {
    int n = blockIdx.x;
    int t = threadIdx.x;
    int r0 = row_of_pair[n * 4 + 0], r1 = row_of_pair[n * 4 + 1];
    int r2 = row_of_pair[n * 4 + 2], r3 = row_of_pair[n * 4 + 3];
    float4 a = ((const float4*)(contrib + (size_t)r0 * DDIM))[t];
    float4 b = ((const float4*)(contrib + (size_t)r1 * DDIM))[t];
    float4 c = ((const float4*)(contrib + (size_t)r2 * DDIM))[t];
    float4 d = ((const float4*)(contrib + (size_t)r3 * DDIM))[t];
    float4 s;
    s.x = a.x + b.x + c.x + d.x;
    s.y = a.y + b.y + c.y + d.y;
    s.z = a.z + b.z + c.z + d.z;
    s.w = a.w + b.w + c.w + d.w;
    ((float4*)(out + (size_t)n * DDIM))[t] = s;
}

extern "C" void kernel_launch(void* const* d_in, const int* in_sizes, int n_in,
                              void* d_out, int out_size, void* d_ws, size_t ws_size,
                              hipStream_t stream) {
    const float* x   = (const float*)d_in[0];
    const float* rw  = (const float*)d_in[1];
    const float* rb  = (const float*)d_in[2];
    const float* gup = (const float*)d_in[3];
    const float* gub = (const float*)d_in[4];
    const float* dwn = (const float*)d_in[5];
    const float* dwb = (const float*)d_in[6];
    float* out = (float*)d_out;

    char* ws = (char*)d_ws;
    size_t off = 0;
    auto alloc = [&](size_t bytes) -> void* {
        void* p = ws + off;
        off += (bytes + 255) & ~(size_t)255;
        return p;
    };
    ushort_t* Ar   = (ushort_t*)alloc((size_t)CAPROWS * DDIM * 2);      // 18.9 MB
    ushort_t* ACT  = (ushort_t*)alloc((size_t)CAPROWS * IDIM * 2);      // 37.7 MB
    float* CONTRIB = (float*)alloc((size_t)CAPROWS * DDIM * 4);         // 37.7 MB
    int*   topk_idx    = (int*)alloc(NTOK * 4 * 4);
    float* topk_w      = (float*)alloc(NTOK * 4 * 4);
    int*   row_of_pair = (int*)alloc(NTOK * 4 * 4);
    int*   row_token   = (int*)alloc(CAPROWS * 4);
    float* row_weight  = (float*)alloc(CAPROWS * 4);
    int*   meta        = (int*)alloc(256);
    int* counts = meta;      int* fill = meta + 8;
    int* base   = meta + 16; int* padcnt = meta + 24;
    int* totalp = meta + 32;

    zero_meta_kernel<<<1, 64, 0, stream>>>(meta);
    router_kernel<<<NTOK / 4, 256, 0, stream>>>(x, rw, rb, topk_idx, topk_w, counts);
    assign_kernel<<<NTOK / 256, 256, 0, stream>>>(topk_idx, topk_w, counts, fill,
                                                  row_token, row_weight, row_of_pair,
                                                  base, padcnt, totalp);
    gather_kernel<<<CAPROWS, 256, 0, stream>>>(x, row_token, base, counts, padcnt, totalp, Ar);
    gemm1_kernel<<<dim3(IDIM / 128, 16, ENUM), 256, 0, stream>>>(Ar, gup, gub, ACT, base, padcnt);
    gemm2_kernel<<<dim3(DDIM / 128, 16, ENUM), 256, 0, stream>>>(ACT, dwn, dwb, row_weight, CONTRIB, base, padcnt);
    combine_kernel<<<NTOK, 256, 0, stream>>>(CONTRIB, row_of_pair, out);
}

// Round 5
// 594.517 us; speedup vs baseline: 1.0584x; 1.0584x over previous
//
#include <hip/hip_runtime.h>
#include <hip/hip_bf16.h>
#include <stdint.h>
#include <math.h>

#define NTOK   2048
#define DDIM   1024
#define ENUM   8
#define IDIM   2048
#define TWOI   4096
#define TOPKN  4
#define CAPROWS 9216   // max padded routed rows: 8192 + 8*127 = 9208 -> 9216

typedef unsigned short ushort_t;
typedef __attribute__((ext_vector_type(8))) short short8;
typedef __attribute__((ext_vector_type(4))) float f4;

__device__ inline ushort_t f2bf(float f) {
    union { float f; uint32_t u; } v; v.f = f;
    uint32_t u = v.u;
    u += 0x7FFFu + ((u >> 16) & 1u);   // RNE
    return (ushort_t)(u >> 16);
}

// packed fp32x2 -> bf16x2 (v_cvt_pk_bf16_f32 on gfx950), lo in low 16 bits
__device__ inline uint32_t pk2(float lo, float hi) {
    __hip_bfloat162 h = __float22bfloat162_rn(make_float2(lo, hi));
    union { __hip_bfloat162 h; uint32_t u; } c; c.h = h;
    return c.u;
}
__device__ inline uint4 cvt8(float4 a, float4 b) {
    uint4 o;
    o.x = pk2(a.x, a.y); o.y = pk2(a.z, a.w);
    o.z = pk2(b.x, b.y); o.w = pk2(b.z, b.w);
    return o;
}

__global__ void zero_meta_kernel(int* meta) {
    if (blockIdx.x == 0 && threadIdx.x < 64) meta[threadIdx.x] = 0;
}

// ---------------- router: fp64 logits (top-4 robust vs fp32 ref noise), fp32 softmax ----
__global__ void router_kernel(const float* __restrict__ x, const float* __restrict__ rw,
                              const float* __restrict__ rb, int* __restrict__ topk_idx,
                              float* __restrict__ topk_w, int* __restrict__ counts) {
    int n = (blockIdx.x * 256 + threadIdx.x) >> 6;   // one wave per token
    int lane = threadIdx.x & 63;
    const float* xr = x + (size_t)n * DDIM;
    double p[ENUM];
#pragma unroll
    for (int e = 0; e < ENUM; ++e) p[e] = 0.0;
    for (int d0 = 0; d0 < DDIM; d0 += 64) {
        double xv = (double)xr[d0 + lane];
#pragma unroll
        for (int e = 0; e < ENUM; ++e) p[e] += xv * (double)rw[e * DDIM + d0 + lane];
    }
#pragma unroll
    for (int e = 0; e < ENUM; ++e) {
        double v = p[e];
#pragma unroll
        for (int off = 32; off > 0; off >>= 1) v += __shfl_xor(v, off, 64);
        p[e] = v + (double)rb[e];
    }
    if (lane == 0) {
        int id[TOPKN]; double lv[TOPKN]; unsigned used = 0;
#pragma unroll
        for (int k = 0; k < TOPKN; ++k) {
            double best = -INFINITY; int bi = 0;
            for (int e = 0; e < ENUM; ++e)
                if (!((used >> e) & 1u) && p[e] > best) { best = p[e]; bi = e; }
            used |= 1u << bi; id[k] = bi; lv[k] = best;
        }
        float lf[TOPKN]; float s = 0.f; float w[TOPKN];
#pragma unroll
        for (int k = 0; k < TOPKN; ++k) lf[k] = (float)lv[k];
#pragma unroll
        for (int k = 0; k < TOPKN; ++k) { w[k] = expf(lf[k] - lf[0]); s += w[k]; }
        float inv = 1.f / s;
#pragma unroll
        for (int k = 0; k < TOPKN; ++k) {
            topk_idx[n * TOPKN + k] = id[k];
            topk_w[n * TOPKN + k] = w[k] * inv;
            atomicAdd(&counts[id[k]], 1);
        }
    }
}

// ---------------- assign routed rows (scan inlined) ----------------
__global__ void assign_kernel(const int* __restrict__ topk_idx, const float* __restrict__ topk_w,
                              const int* __restrict__ counts, int* __restrict__ fill,
                              int* __restrict__ row_token, float* __restrict__ row_weight,
                              int* __restrict__ row_of_pair,
                              int* __restrict__ base, int* __restrict__ padcnt,
                              int* __restrict__ totalp) {
    int baseL[ENUM]; int run = 0;
#pragma unroll
    for (int e = 0; e < ENUM; ++e) {
        baseL[e] = run;
        run += (counts[e] + 127) & ~127;
    }
    int n = blockIdx.x * 256 + threadIdx.x;
    if (n == 0) {
#pragma unroll
        for (int e = 0; e < ENUM; ++e) {
            base[e] = baseL[e];
            padcnt[e] = (counts[e] + 127) & ~127;
        }
        *totalp = run;
    }
    if (n >= NTOK) return;
    for (int k = 0; k < TOPKN; ++k) {
        int e = topk_idx[n * TOPKN + k];
        int pos = atomicAdd(&fill[e], 1);
        int row = baseL[e] + pos;
        row_token[row] = n;
        row_weight[row] = topk_w[n * TOPKN + k];
        row_of_pair[n * TOPKN + k] = row;
    }
}

// ---------------- gather tokens -> bf16 A matrix (zero pad rows) ----------------
__global__ void gather_kernel(const float* __restrict__ x, const int* __restrict__ row_token,
                              const int* __restrict__ base, const int* __restrict__ counts,
                              const int* __restrict__ padcnt, const int* __restrict__ totalp,
                              ushort_t* __restrict__ A) {
    int r = blockIdx.x;
    if (r >= *totalp) return;
    int e = 0;
#pragma unroll
    for (int i = 0; i < ENUM; ++i) if (r >= base[i] + padcnt[i]) e = i + 1;
    bool valid = (r - base[e]) < counts[e];
    int t = threadIdx.x;
    float4 v = make_float4(0.f, 0.f, 0.f, 0.f);
    if (valid) {
        int n = row_token[r];
        v = ((const float4*)(x + (size_t)n * DDIM))[t];
    }
    ushort4 o; o.x = f2bf(v.x); o.y = f2bf(v.y); o.z = f2bf(v.z); o.w = f2bf(v.w);
    ((ushort4*)(A + (size_t)r * DDIM))[t] = o;
}

// ---------------- GEMM1: software-pipelined, fp32 weights cvt'd in-flight ----------
// 128x128 tile per (gate,up); dbuf LDS; 1 barrier/iter; prefetch tile i+1 in VGPRs
// while MFMAs consume tile i from LDS.
__global__ __launch_bounds__(256, 2)
void gemm1_kernel(const ushort_t* __restrict__ A, const float* __restrict__ gup,
                  const float* __restrict__ gub, ushort_t* __restrict__ act,
                  const int* __restrict__ base, const int* __restrict__ padcnt) {
    const int e = blockIdx.z;
    const int mt = blockIdx.y;
    if (mt * 128 >= padcnt[e]) return;
    const int nt = blockIdx.x;               // 0..15 -> I-dim tile
    const int row0 = base[e] + mt * 128;
    __shared__ ushort_t ldsA[2][128 * 32];
    __shared__ ushort_t ldsG[2][128 * 32];
    __shared__ ushort_t ldsU[2][128 * 32];
    f4 accg[4][4], accu[4][4];
    const f4 zero = {0.f, 0.f, 0.f, 0.f};
#pragma unroll
    for (int i = 0; i < 4; ++i)
#pragma unroll
        for (int j = 0; j < 4; ++j) { accg[i][j] = zero; accu[i][j] = zero; }

    const int t = threadIdx.x;
    const int lane = t & 63;
    const int wid = t >> 6;
    const int wm = wid >> 1, wn = wid & 1;
    const int r15 = lane & 15, quad = lane >> 4;
    const int sr = t >> 2;            // 0..63
    const int sc = (t & 3) << 3;      // {0,8,16,24}

    const ushort_t* aA  = A + (size_t)(row0 + sr) * DDIM + sc;
    const ushort_t* aA2 = aA + (size_t)64 * DDIM;
    const float* gG  = gup + ((size_t)e * TWOI + nt * 128 + sr) * DDIM + sc;
    const float* gG2 = gG + (size_t)64 * DDIM;
    const float* gU  = gG + (size_t)IDIM * DDIM;
    const float* gU2 = gU + (size_t)64 * DDIM;

    const int lo = sr * 32 + sc;      // LDS offset for staging row

    uint4  ra0, ra1;                  // A prefetch (bf16 x8 each)
    float4 rg0a, rg0b, rg1a, rg1b;    // gate fp32 prefetch
    float4 ru0a, ru0b, ru1a, ru1b;    // up fp32 prefetch

    // prologue: stage tile 0 into buf 0
    ra0 = *((const uint4*)aA);          ra1 = *((const uint4*)aA2);
    rg0a = ((const float4*)gG)[0];      rg0b = ((const float4*)gG)[1];
    rg1a = ((const float4*)gG2)[0];     rg1b = ((const float4*)gG2)[1];
    ru0a = ((const float4*)gU)[0];      ru0b = ((const float4*)gU)[1];
    ru1a = ((const float4*)gU2)[0];     ru1b = ((const float4*)gU2)[1];
    *((uint4*)(ldsA[0] + lo)) = ra0;   *((uint4*)(ldsA[0] + lo + 64 * 32)) = ra1;
    *((uint4*)(ldsG[0] + lo)) = cvt8(rg0a, rg0b);
    *((uint4*)(ldsG[0] + lo + 64 * 32)) = cvt8(rg1a, rg1b);
    *((uint4*)(ldsU[0] + lo)) = cvt8(ru0a, ru0b);
    *((uint4*)(ldsU[0] + lo + 64 * 32)) = cvt8(ru1a, ru1b);

    const int NK = DDIM / 32;
    for (int i = 0; i < NK; ++i) {
        const int cur = i & 1, nxt = cur ^ 1;
        const int k1 = (i + 1) * 32;
        // 1. prefetch tile i+1 (issue loads; consumed after MFMA block)
        if (i + 1 < NK) {
            ra0 = *((const uint4*)(aA + k1));     ra1 = *((const uint4*)(aA2 + k1));
            rg0a = ((const float4*)(gG + k1))[0];  rg0b = ((const float4*)(gG + k1))[1];
            rg1a = ((const float4*)(gG2 + k1))[0]; rg1b = ((const float4*)(gG2 + k1))[1];
            ru0a = ((const float4*)(gU + k1))[0];  ru0b = ((const float4*)(gU + k1))[1];
            ru1a = ((const float4*)(gU2 + k1))[0]; ru1b = ((const float4*)(gU2 + k1))[1];
        }
        __syncthreads();               // buf[cur] now visible to all waves
        // 2. compute on tile i
        short8 af[4], gf[4], uf[4];
#pragma unroll
        for (int j = 0; j < 4; ++j) {
            af[j] = *(const short8*)(ldsA[cur] + (wm * 64 + j * 16 + r15) * 32 + quad * 8);
            gf[j] = *(const short8*)(ldsG[cur] + (wn * 64 + j * 16 + r15) * 32 + quad * 8);
            uf[j] = *(const short8*)(ldsU[cur] + (wn * 64 + j * 16 + r15) * 32 + quad * 8);
        }
#pragma unroll
        for (int mi = 0; mi < 4; ++mi)
#pragma unroll
            for (int ni = 0; ni < 4; ++ni) {
                accg[mi][ni] = __builtin_amdgcn_mfma_f32_16x16x32_bf16(af[mi], gf[ni], accg[mi][ni], 0, 0, 0);
                accu[mi][ni] = __builtin_amdgcn_mfma_f32_16x16x32_bf16(af[mi], uf[ni], accu[mi][ni], 0, 0, 0);
            }
        // 3. stage tile i+1 into buf[nxt] (loads retire here, hidden by MFMAs above)
        if (i + 1 < NK) {
            *((uint4*)(ldsA[nxt] + lo)) = ra0;   *((uint4*)(ldsA[nxt] + lo + 64 * 32)) = ra1;
            *((uint4*)(ldsG[nxt] + lo)) = cvt8(rg0a, rg0b);
            *((uint4*)(ldsG[nxt] + lo + 64 * 32)) = cvt8(rg1a, rg1b);
            *((uint4*)(ldsU[nxt] + lo)) = cvt8(ru0a, ru0b);
            *((uint4*)(ldsU[nxt] + lo + 64 * 32)) = cvt8(ru1a, ru1b);
        }
    }

    const int colbase = nt * 128 + wn * 64;
    const int rowbase = row0 + wm * 64;
#pragma unroll
    for (int ni = 0; ni < 4; ++ni) {
        const int col = colbase + ni * 16 + r15;            // 0..2047 (I dim)
        const float bg = gub[e * TWOI + col];
        const float bu = gub[e * TWOI + IDIM + col];
#pragma unroll
        for (int mi = 0; mi < 4; ++mi) {
#pragma unroll
            for (int r = 0; r < 4; ++r) {
                const int row = rowbase + mi * 16 + quad * 4 + r;
                float g = fminf(accg[mi][ni][r] + bg, 7.0f);
                float u = fminf(fmaxf(accu[mi][ni][r] + bu, -7.0f), 7.0f);
                float a = (u + 1.0f) * g / (1.0f + __expf(-1.702f * g));
                act[(size_t)row * IDIM + col] = f2bf(a);
            }
        }
    }
}

// ---------------- GEMM2: pipelined, contrib = (act @ Wd^T + bias) * route_weight -------
__global__ __launch_bounds__(256, 3)
void gemm2_kernel(const ushort_t* __restrict__ A, const float* __restrict__ dwn,
                  const float* __restrict__ dwb, const float* __restrict__ row_weight,
                  float* __restrict__ contrib,
                  const int* __restrict__ base, const int* __restrict__ padcnt) {
    const int e = blockIdx.z;
    const int mt = blockIdx.y;
    if (mt * 128 >= padcnt[e]) return;
    const int nt = blockIdx.x;
    const int row0 = base[e] + mt * 128;
    __shared__ ushort_t ldsA[2][128 * 32];
    __shared__ ushort_t ldsB[2][128 * 32];
    f4 acc[4][4];
    const f4 zero = {0.f, 0.f, 0.f, 0.f};
#pragma unroll
    for (int i = 0; i < 4; ++i)
#pragma unroll
        for (int j = 0; j < 4; ++j) acc[i][j] = zero;

    const int t = threadIdx.x;
    const int lane = t & 63;
    const int wid = t >> 6;
    const int wm = wid >> 1, wn = wid & 1;
    const int r15 = lane & 15, quad = lane >> 4;
    const int sr = t >> 2;
    const int sc = (t & 3) << 3;

    const ushort_t* aA  = A + (size_t)(row0 + sr) * IDIM + sc;
    const ushort_t* aA2 = aA + (size_t)64 * IDIM;
    const float* gB  = dwn + ((size_t)e * DDIM + nt * 128 + sr) * IDIM + sc;
    const float* gB2 = gB + (size_t)64 * IDIM;

    const int lo = sr * 32 + sc;

    uint4  ra0, ra1;
    float4 rb0a, rb0b, rb1a, rb1b;

    ra0 = *((const uint4*)aA);          ra1 = *((const uint4*)aA2);
    rb0a = ((const float4*)gB)[0];      rb0b = ((const float4*)gB)[1];
    rb1a = ((const float4*)gB2)[0];     rb1b = ((const float4*)gB2)[1];
    *((uint4*)(ldsA[0] + lo)) = ra0;   *((uint4*)(ldsA[0] + lo + 64 * 32)) = ra1;
    *((uint4*)(ldsB[0] + lo)) = cvt8(rb0a, rb0b);
    *((uint4*)(ldsB[0] + lo + 64 * 32)) = cvt8(rb1a, rb1b);

    const int NK = IDIM / 32;
    for (int i = 0; i < NK; ++i) {
        const int cur = i & 1, nxt = cur ^ 1;
        const int k1 = (i + 1) * 32;
        if (i + 1 < NK) {
            ra0 = *((const uint4*)(aA + k1));     ra1 = *((const uint4*)(aA2 + k1));
            rb0a = ((const float4*)(gB + k1))[0];  rb0b = ((const float4*)(gB + k1))[1];
            rb1a = ((const float4*)(gB2 + k1))[0]; rb1b = ((const float4*)(gB2 + k1))[1];
        }
        __syncthreads();
        short8 af[4], bfv[4];
#pragma unroll
        for (int j = 0; j < 4; ++j) {
            af[j]  = *(const short8*)(ldsA[cur] + (wm * 64 + j * 16 + r15) * 32 + quad * 8);
            bfv[j] = *(const short8*)(ldsB[cur] + (wn * 64 + j * 16 + r15) * 32 + quad * 8);
        }
#pragma unroll
        for (int mi = 0; mi < 4; ++mi)
#pragma unroll
            for (int ni = 0; ni < 4; ++ni)
                acc[mi][ni] = __builtin_amdgcn_mfma_f32_16x16x32_bf16(af[mi], bfv[ni], acc[mi][ni], 0, 0, 0);
        if (i + 1 < NK) {
            *((uint4*)(ldsA[nxt] + lo)) = ra0;   *((uint4*)(ldsA[nxt] + lo + 64 * 32)) = ra1;
            *((uint4*)(ldsB[nxt] + lo)) = cvt8(rb0a, rb0b);
            *((uint4*)(ldsB[nxt] + lo + 64 * 32)) = cvt8(rb1a, rb1b);
        }
    }

    const int colbase = nt * 128 + wn * 64;
    const int rowbase = row0 + wm * 64;
#pragma unroll
    for (int mi = 0; mi < 4; ++mi) {
#pragma unroll
        for (int r = 0; r < 4; ++r) {
            const int row = rowbase + mi * 16 + quad * 4 + r;
            const float w = row_weight[row];
#pragma unroll
            for (int ni = 0; ni < 4; ++ni) {
                const int col = colbase + ni * 16 + r15;
                contrib[(size_t)row * DDIM + col] = (acc[mi][ni][r] + dwb[e * DDIM + col]) * w;
            }
        }
    }
}

// ---------------- combine 4 contributions per token ----------------
__global__ void combine_kernel(const float* __restrict__ contrib, const int* __restrict__ row_of_pair,
                               float* __restrict__ out) {
    int n = blockIdx.x;
    int t = threadIdx.x;
    int r0 = row_of_pair[n * 4 + 0], r1 = row_of_pair[n * 4 + 1];
    int r2 = row_of_pair[n * 4 + 2], r3 = row_of_pair[n * 4 + 3];
    float4 a = ((const float4*)(contrib + (size_t)r0 * DDIM))[t];
    float4 b = ((const float4*)(contrib + (size_t)r1 * DDIM))[t];
    float4 c = ((const float4*)(contrib + (size_t)r2 * DDIM))[t];
    float4 d = ((const float4*)(contrib + (size_t)r3 * DDIM))[t];
    float4 s;
    s.x = a.x + b.x + c.x + d.x;
    s.y = a.y + b.y + c.y + d.y;
    s.z = a.z + b.z + c.z + d.z;
    s.w = a.w + b.w + c.w + d.w;
    ((float4*)(out + (size_t)n * DDIM))[t] = s;
}

extern "C" void kernel_launch(void* const* d_in, const int* in_sizes, int n_in,
                              void* d_out, int out_size, void* d_ws, size_t ws_size,
                              hipStream_t stream) {
    const float* x   = (const float*)d_in[0];
    const float* rw  = (const float*)d_in[1];
    const float* rb  = (const float*)d_in[2];
    const float* gup = (const float*)d_in[3];
    const float* gub = (const float*)d_in[4];
    const float* dwn = (const float*)d_in[5];
    const float* dwb = (const float*)d_in[6];
    float* out = (float*)d_out;

    char* ws = (char*)d_ws;
    size_t off = 0;
    auto alloc = [&](size_t bytes) -> void* {
        void* p = ws + off;
        off += (bytes + 255) & ~(size_t)255;
        return p;
    };
    ushort_t* Ar   = (ushort_t*)alloc((size_t)CAPROWS * DDIM * 2);      // 18.9 MB
    ushort_t* ACT  = (ushort_t*)alloc((size_t)CAPROWS * IDIM * 2);      // 37.7 MB
    float* CONTRIB = (float*)alloc((size_t)CAPROWS * DDIM * 4);         // 37.7 MB
    int*   topk_idx    = (int*)alloc(NTOK * 4 * 4);
    float* topk_w      = (float*)alloc(NTOK * 4 * 4);
    int*   row_of_pair = (int*)alloc(NTOK * 4 * 4);
    int*   row_token   = (int*)alloc(CAPROWS * 4);
    float* row_weight  = (float*)alloc(CAPROWS * 4);
    int*   meta        = (int*)alloc(256);
    int* counts = meta;      int* fill = meta + 8;
    int* base   = meta + 16; int* padcnt = meta + 24;
    int* totalp = meta + 32;

    zero_meta_kernel<<<1, 64, 0, stream>>>(meta);
    router_kernel<<<NTOK / 4, 256, 0, stream>>>(x, rw, rb, topk_idx, topk_w, counts);
    assign_kernel<<<NTOK / 256, 256, 0, stream>>>(topk_idx, topk_w, counts, fill,
                                                  row_token, row_weight, row_of_pair,
                                                  base, padcnt, totalp);
    gather_kernel<<<CAPROWS, 256, 0, stream>>>(x, row_token, base, counts, padcnt, totalp, Ar);
    gemm1_kernel<<<dim3(IDIM / 128, 16, ENUM), 256, 0, stream>>>(Ar, gup, gub, ACT, base, padcnt);
    gemm2_kernel<<<dim3(DDIM / 128, 16, ENUM), 256, 0, stream>>>(ACT, dwn, dwb, row_weight, CONTRIB, base, padcnt);
    combine_kernel<<<NTOK, 256, 0, stream>>>(CONTRIB, row_of_pair, out);
}